// Round 10
// baseline (389.083 us; speedup 1.0000x reference)
//
#include <hip/hip_runtime.h>
#include <hip/hip_bf16.h>
#include <stdint.h>

#define TT   512
#define BB   128
#define DIN  256
#define DH   512
#define DOUT 256
#define NV   (BB*DH)     // 65536
#define NLOG (BB*DOUT)   // 32768
#define MTOT (TT*BB)     // 65536

typedef unsigned short u16;
typedef __attribute__((ext_vector_type(8))) short bf16x8;
typedef __attribute__((ext_vector_type(4))) float f32x4;

__device__ __forceinline__ void gld_lds16(const float* g, float* l) {
    __builtin_amdgcn_global_load_lds(
        (const __attribute__((address_space(1))) void*)g,
        (__attribute__((address_space(3))) void*)l, 16, 0, 0);
}

// ========== X transpose: X[MTOT][DIN] -> XT[DIN][MTOT] ======================
// Enables global_load_lds staging of A in [k][m] layout (gld_lds cannot
// transpose: wave-uniform LDS base + lane*16 only).
__global__ __launch_bounds__(256) void trspX_k(
    const float* __restrict__ X, float* __restrict__ XT)
{
    __shared__ float T[64][65];
    const int m0 = blockIdx.x * 64, k0 = blockIdx.y * 64;
    const int t = threadIdx.x;
    #pragma unroll
    for (int p = 0; p < 4; ++p) {
        const int idx = p*256 + t;
        const int rr = idx >> 4, cc = (idx & 15)*4;
        float4 v = *reinterpret_cast<const float4*>(
            &X[(size_t)(m0+rr)*DIN + k0 + cc]);
        T[rr][cc+0] = v.x; T[rr][cc+1] = v.y;
        T[rr][cc+2] = v.z; T[rr][cc+3] = v.w;
    }
    __syncthreads();
    #pragma unroll
    for (int p = 0; p < 4; ++p) {
        const int idx = p*256 + t;
        const int kk = idx >> 4, mm = (idx & 15)*4;
        float4 o;
        o.x = T[mm+0][kk]; o.y = T[mm+1][kk];
        o.z = T[mm+2][kk]; o.w = T[mm+3][kk];
        *reinterpret_cast<float4*>(&XT[(size_t)(k0+kk)*MTOT + m0 + mm]) = o;
    }
}

// ========== GEMM1: CUR = X @ Win + bin, strict f32 (bitwise-np) =============
// 128x256 tile, 256 threads, 8x16/thread, BK=16. R10: 3-stage software
// pipeline (T3+T4): triple-buffered LDS, ALL staging via global_load_lds
// (zero staging regs — R9 precedent: 128 VGPR, no spill), counted
// s_waitcnt vmcnt(6) + bare s_barrier (never drain vmcnt to 0 in-loop).
// R9's __syncthreads drained the full load queue 16x per block = ~40% stall.
// Numerics: single accumulator per output, fmaf over k ASCENDING — bitwise
// vs numpy reference; spikes feed back through the threshold. DO NOT ALTER.
__global__ __launch_bounds__(256) void gemm1_f32(
    const float* __restrict__ XT, const float* __restrict__ Win,
    const float* __restrict__ bin, float* __restrict__ CUR)
{
    __shared__ __align__(16) float As[3][16][128];   // [stage][k][m] (gld_lds linear)
    __shared__ __align__(16) float Bs[3][16][256];   // [stage][k][n] (gld_lds linear)
    const int bm = blockIdx.x * 128;
    const int bn = blockIdx.y * 256;
    const int t  = threadIdx.x;
    const int lane = t & 63, w = t >> 6;  // 4 waves
    const int tx = t & 15, ty = t >> 4;   // 16 col-groups x 16 row-groups
    float acc[8][16] = {};                // row ty*8+i, col g*64+tx*4+j

    // A-tile 16x128 ([k][m]): 1 gld_lds = 1KB = 2 rows. Wave w: rows 4w..4w+3.
    #define G1_STAGE_A(sb_, k0_) do { \
        _Pragma("unroll") \
        for (int q = 0; q < 2; ++q) { \
            const int rbase = w*4 + q*2; \
            gld_lds16(&XT[(size_t)((k0_)+rbase+(lane>>5))*MTOT + bm + (lane&31)*4], \
                      &As[sb_][rbase][0]); \
        } \
    } while (0)
    // B-tile 16x256: 1 gld_lds = 1KB = 1 row. Wave w: rows q*4+w, q=0..3.
    #define G1_STAGE_B(sb_, k0_) do { \
        _Pragma("unroll") \
        for (int q = 0; q < 4; ++q) { \
            const int r = q*4 + w; \
            gld_lds16(&Win[(size_t)((k0_)+r)*DH + bn + lane*4], &Bs[sb_][r][0]); \
        } \
    } while (0)
    // 6 gld_lds per wave per stage (2 A + 4 B) -> steady-state vmcnt(6)
    // keeps the NEXT tile's 6 loads in flight across the barrier.
    #define G1_COMPUTE(sb_) do { \
        _Pragma("unroll 4") \
        for (int kk = 0; kk < 16; ++kk) { \
            float a[8], b[16]; \
            float4 a0 = *reinterpret_cast<const float4*>(&As[sb_][kk][ty*8]); \
            float4 a1 = *reinterpret_cast<const float4*>(&As[sb_][kk][ty*8+4]); \
            a[0]=a0.x; a[1]=a0.y; a[2]=a0.z; a[3]=a0.w; \
            a[4]=a1.x; a[5]=a1.y; a[6]=a1.z; a[7]=a1.w; \
            _Pragma("unroll") \
            for (int g = 0; g < 4; ++g) { \
                float4 bq = *reinterpret_cast<const float4*>(&Bs[sb_][kk][g*64 + tx*4]); \
                b[g*4+0]=bq.x; b[g*4+1]=bq.y; b[g*4+2]=bq.z; b[g*4+3]=bq.w; \
            } \
            _Pragma("unroll") \
            for (int i = 0; i < 8; ++i) \
                _Pragma("unroll") \
                for (int j = 0; j < 16; ++j) \
                    acc[i][j] = fmaf(a[i], b[j], acc[i][j]); \
        } \
    } while (0)

    // prologue: stage tiles 0 and 1 (12 loads in flight)
    G1_STAGE_A(0, 0);  G1_STAGE_B(0, 0);
    G1_STAGE_A(1, 16); G1_STAGE_B(1, 16);

    // main loop: tiles 0..14; tile t lives in buffer t%3
    #pragma unroll 1
    for (int tI = 0; tI < 15; ++tI) {
        const int sb = tI % 3;
        // wait for tile tI's 6 loads (oldest); tile tI+1's 6 stay in flight
        asm volatile("s_waitcnt vmcnt(6)" ::: "memory");
        __builtin_amdgcn_sched_barrier(0);
        __builtin_amdgcn_s_barrier();
        __builtin_amdgcn_sched_barrier(0);
        G1_COMPUTE(sb);
        __builtin_amdgcn_sched_barrier(0);
        __builtin_amdgcn_s_barrier();     // all waves done reading buf (tI-1)%3
        __builtin_amdgcn_sched_barrier(0);
        if (tI + 2 < 16) {                // stage tile tI+2 into buf (tI+2)%3
            const int k2 = (tI + 2) * 16;
            const int s2 = (tI + 2) % 3;
            G1_STAGE_A(s2, k2);
            G1_STAGE_B(s2, k2);
        }
    }
    // epilogue iter: tile 15 (buffer 15%3 = 0), drain all loads
    asm volatile("s_waitcnt vmcnt(0)" ::: "memory");
    __builtin_amdgcn_sched_barrier(0);
    __builtin_amdgcn_s_barrier();
    __builtin_amdgcn_sched_barrier(0);
    G1_COMPUTE(0);

    #pragma unroll
    for (int i = 0; i < 8; ++i) {
        const int row = bm + ty*8 + i;
        #pragma unroll
        for (int g = 0; g < 4; ++g) {
            const int col = bn + g*64 + tx*4;
            float4 o;
            o.x = __fadd_rn(acc[i][g*4+0], bin[col+0]);
            o.y = __fadd_rn(acc[i][g*4+1], bin[col+1]);
            o.z = __fadd_rn(acc[i][g*4+2], bin[col+2]);
            o.w = __fadd_rn(acc[i][g*4+3], bin[col+3]);
            *reinterpret_cast<float4*>(&CUR[(size_t)row*DH + col]) = o;
        }
    }
}

// ========== scan: strict-f32 recurrence, 32-deep load pipeline ==============
__global__ __launch_bounds__(256) void scan_k(
    const float* __restrict__ CUR, const float* __restrict__ wrec,
    u16* __restrict__ SPK, unsigned int* __restrict__ cnt)
{
    const int i = blockIdx.x*256 + threadIdx.x;
    float v = 0.0f;                       // V0 = 0
    const float w = wrec[i & (DH-1)];
    int c = 0;
    float cur[32], nxt[32];
    #pragma unroll
    for (int u = 0; u < 32; ++u) cur[u] = CUR[(size_t)u*NV + i];
    for (int t0 = 0; t0 < TT; t0 += 32) {
        if (t0 + 32 < TT) {
            #pragma unroll
            for (int u = 0; u < 32; ++u) nxt[u] = CUR[(size_t)(t0+32+u)*NV + i];
        }
        u16 sp[32];
        #pragma unroll
        for (int u = 0; u < 32; ++u) {
            const bool s = v > 1.0f;      // (V-1>0) <=> V>1 exactly in f32
            sp[u] = s ? (u16)0x3F80 : (u16)0;   // bf16 1.0 / 0.0
            c += (int)s;
            float t1 = __fmul_rn(0.9f, v);
            float t2 = __fadd_rn(t1, cur[u]);
            float t3 = __fadd_rn(t2, s ? w : 0.0f);
            v = __fsub_rn(t3, s ? 1.0f : 0.0f);
        }
        #pragma unroll
        for (int u = 0; u < 32; ++u) SPK[(size_t)(t0+u)*NV + i] = sp[u];
        #pragma unroll
        for (int u = 0; u < 32; ++u) cur[u] = nxt[u];
    }
    #pragma unroll
    for (int o = 32; o > 0; o >>= 1) c += __shfl_down(c, o, 64);
    if ((threadIdx.x & 63) == 0) atomicAdd(cnt, (unsigned int)c);
}

// ========== W_head -> bf16 transposed [DOUT][DH] ============================
__global__ __launch_bounds__(256) void trsp_k(
    const float* __restrict__ Wh, u16* __restrict__ WhT)
{
    const int id = blockIdx.x*256 + threadIdx.x;   // DOUT*DH
    const int n = id >> 9, k = id & (DH-1);
    __hip_bfloat16 h = __float2bfloat16(Wh[(size_t)k*DOUT + n]);
    WhT[id] = *reinterpret_cast<u16*>(&h);
}

// ========== GEMM2: logits = SPK @ Whead + bhead, bf16 MFMA ==================
// 128x128 tile, 4 waves (2x2), BK=32, 16x16x32 MFMA, double-buffered LDS,
// one barrier per k-step. Chunk XOR-swizzle c^(srow&3) kills frag-read
// bank conflicts.
__global__ __launch_bounds__(256) void gemm2_mfma(
    const u16* __restrict__ SPK, const u16* __restrict__ WhT,
    const float* __restrict__ bh, float* __restrict__ Y)
{
    __shared__ __align__(16) u16 Ab[2][128*32];
    __shared__ __align__(16) u16 Bb[2][128*32];
    const int bm = blockIdx.x * 128;
    const int bn = blockIdx.y * 128;
    const int t = threadIdx.x;
    const int lane = t & 63, wid = t >> 6;
    const int wr = wid >> 1, wc = wid & 1;
    const int srow = t >> 1, shf = t & 1;
    uint4 va[2], vb[2];
    f32x4 acc[4][4];
    #pragma unroll
    for (int m = 0; m < 4; ++m)
        #pragma unroll
        for (int n = 0; n < 4; ++n) acc[m][n] = (f32x4){0.f,0.f,0.f,0.f};

    #define G2_LOAD(k0) do { \
        _Pragma("unroll") \
        for (int q = 0; q < 2; ++q) { \
            const int c = shf*2 + q; \
            va[q] = *reinterpret_cast<const uint4*>(&SPK[(size_t)(bm+srow)*DH + (k0) + c*8]); \
            vb[q] = *reinterpret_cast<const uint4*>(&WhT[(size_t)(bn+srow)*DH + (k0) + c*8]); \
        } \
    } while (0)
    #define G2_WRITE(nb) do { \
        _Pragma("unroll") \
        for (int q = 0; q < 2; ++q) { \
            const int c = shf*2 + q; \
            *reinterpret_cast<uint4*>(&Ab[nb][srow*32 + ((c ^ (srow&3))*8)]) = va[q]; \
            *reinterpret_cast<uint4*>(&Bb[nb][srow*32 + ((c ^ (srow&3))*8)]) = vb[q]; \
        } \
    } while (0)

    G2_LOAD(0);
    G2_WRITE(0);
    __syncthreads();

    int nb = 0;
    for (int k0 = 0; k0 < DH; k0 += 32) {
        const int nxt = k0 + 32;
        if (nxt < DH) G2_LOAD(nxt);
        const int l15 = lane & 15, lc = lane >> 4;
        bf16x8 af[4], bfr[4];
        #pragma unroll
        for (int m = 0; m < 4; ++m) {
            const int r = wr*64 + m*16 + l15;
            af[m] = *reinterpret_cast<const bf16x8*>(&Ab[nb][r*32 + ((lc ^ (r&3))*8)]);
        }
        #pragma unroll
        for (int n = 0; n < 4; ++n) {
            const int r = wc*64 + n*16 + l15;
            bfr[n] = *reinterpret_cast<const bf16x8*>(&Bb[nb][r*32 + ((lc ^ (r&3))*8)]);
        }
        #pragma unroll
        for (int m = 0; m < 4; ++m)
            #pragma unroll
            for (int n = 0; n < 4; ++n)
                acc[m][n] = __builtin_amdgcn_mfma_f32_16x16x32_bf16(
                    af[m], bfr[n], acc[m][n], 0, 0, 0);
        if (nxt < DH) G2_WRITE(nb^1);
        __syncthreads();
        nb ^= 1;
    }
    // epilogue: D col = lane&15, row = (lane>>4)*4 + r
    #pragma unroll
    for (int m = 0; m < 4; ++m)
        #pragma unroll
        for (int n = 0; n < 4; ++n) {
            const int row0 = bm + wr*64 + m*16 + (lane >> 4)*4;
            const int col  = bn + wc*64 + n*16 + (lane & 15);
            const float bv = bh[col];
            #pragma unroll
            for (int r = 0; r < 4; ++r)
                Y[(size_t)(row0 + r)*DOUT + col] = acc[m][n][r] + bv;
        }
}

// ========== readout: mean over T (two-stage, deterministic) =================
__global__ __launch_bounds__(256) void readout1(
    const float* __restrict__ L, double* __restrict__ P)
{
    const int j = blockIdx.x*256 + threadIdx.x;
    const int p = blockIdx.y;
    double s = 0.0;
    for (int u = 0; u < 64; ++u)
        s += (double)L[(size_t)(p*64 + u)*NLOG + j];
    P[(size_t)p*NLOG + j] = s;
}
__global__ __launch_bounds__(256) void readout2(
    const double* __restrict__ P, float* __restrict__ R,
    const unsigned int* __restrict__ cnt, float* __restrict__ srate)
{
    const int j = blockIdx.x*256 + threadIdx.x;
    double s = 0.0;
    #pragma unroll
    for (int p = 0; p < 8; ++p) s += P[(size_t)p*NLOG + j];
    R[j] = (float)(s / (double)TT);
    if (j == 0)
        srate[0] = (float)((double)cnt[0] / ((double)TT * (double)NV));
}

// ============================================================================
extern "C" void kernel_launch(void* const* d_in, const int* in_sizes, int n_in,
                              void* d_out, int out_size, void* d_ws, size_t ws_size,
                              hipStream_t stream)
{
    const float* x     = (const float*)d_in[0];   // [512][128][256]
    const float* Win   = (const float*)d_in[1];   // [256][512]
    const float* bin   = (const float*)d_in[2];   // [512]
    const float* wrec  = (const float*)d_in[3];   // [512]
    const float* Whead = (const float*)d_in[4];   // [512][256]
    const float* bhead = (const float*)d_in[5];   // [256]

    float* out     = (float*)d_out;
    float* readout = out;                           // 32768
    float* logits  = out + NLOG;                    // 512*32768
    float* srate   = out + NLOG + (size_t)TT*NLOG;  // 1

    char* w = (char*)d_ws;
    size_t off = 0;
    float* CUR = (float*)(w + off);  off += (size_t)TT*NV*4;      // 128 MB
    u16*   SPK = (u16*)  (w + off);  off += (size_t)TT*NV*2;      //  64 MB
    u16*   WhT = (u16*)  (w + off);  off += (size_t)DOUT*DH*2;    // 256 KB
    double* P  = (double*)(w + off); off += (size_t)8*NLOG*8;     //   2 MB
    unsigned int* cnt = (unsigned int*)(w + off);
    // XT (64 MB) overlays SPK: XT is consumed by gemm1, dead before scan
    // writes SPK. DIN*MTOT*4 == TT*NV*2 exactly.
    float* XT = (float*)SPK;

    hipMemsetAsync(cnt, 0, 256, stream);
    trspX_k<<<dim3(MTOT/64, DIN/64), 256, 0, stream>>>(x, XT);
    trsp_k<<<DOUT*DH/256, 256, 0, stream>>>(Whead, WhT);
    gemm1_f32<<<dim3(MTOT/128, DH/256), 256, 0, stream>>>(XT, Win, bin, CUR);
    scan_k<<<NV/256, 256, 0, stream>>>(CUR, wrec, SPK, cnt);
    gemm2_mfma<<<dim3(MTOT/128, DOUT/128), 256, 0, stream>>>(SPK, WhT, bhead, logits);
    readout1<<<dim3(NLOG/256, 8), 256, 0, stream>>>(logits, P);
    readout2<<<NLOG/256, 256, 0, stream>>>(P, readout, cnt, srate);
}

// Round 11
// 339.107 us; speedup vs baseline: 1.1474x; 1.1474x over previous
//
#include <hip/hip_runtime.h>
#include <hip/hip_bf16.h>
#include <stdint.h>

#define TT   512
#define BB   128
#define DIN  256
#define DH   512
#define DOUT 256
#define NV   (BB*DH)     // 65536
#define NLOG (BB*DOUT)   // 32768
#define MTOT (TT*BB)     // 65536

typedef unsigned short u16;
typedef unsigned char  u8;
typedef __attribute__((ext_vector_type(8))) short bf16x8;
typedef __attribute__((ext_vector_type(4))) float f32x4;

__device__ __forceinline__ void gld_lds16(const float* g, float* l) {
    __builtin_amdgcn_global_load_lds(
        (const __attribute__((address_space(1))) void*)g,
        (__attribute__((address_space(3))) void*)l, 16, 0, 0);
}

// expand 8 spike bytes (0/1) -> 4 packed bf16 pairs (0x3F80 / 0)
__device__ __forceinline__ uint4 expand8(uint64_t x) {
    uint32_t h[8];
    #pragma unroll
    for (int j = 0; j < 8; ++j)
        h[j] = ((x >> (8*j)) & 0xFFull) ? 0x3F80u : 0u;
    uint4 r;
    r.x = h[0] | (h[1] << 16); r.y = h[2] | (h[3] << 16);
    r.z = h[4] | (h[5] << 16); r.w = h[6] | (h[7] << 16);
    return r;
}

// ========== X transpose: X[MTOT][DIN] -> XT[DIN][MTOT] ======================
__global__ __launch_bounds__(256) void trspX_k(
    const float* __restrict__ X, float* __restrict__ XT)
{
    __shared__ float T[64][65];
    const int m0 = blockIdx.x * 64, k0 = blockIdx.y * 64;
    const int t = threadIdx.x;
    #pragma unroll
    for (int p = 0; p < 4; ++p) {
        const int idx = p*256 + t;
        const int rr = idx >> 4, cc = (idx & 15)*4;
        float4 v = *reinterpret_cast<const float4*>(
            &X[(size_t)(m0+rr)*DIN + k0 + cc]);
        T[rr][cc+0] = v.x; T[rr][cc+1] = v.y;
        T[rr][cc+2] = v.z; T[rr][cc+3] = v.w;
    }
    __syncthreads();
    #pragma unroll
    for (int p = 0; p < 4; ++p) {
        const int idx = p*256 + t;
        const int kk = idx >> 4, mm = (idx & 15)*4;
        float4 o;
        o.x = T[mm+0][kk]; o.y = T[mm+1][kk];
        o.z = T[mm+2][kk]; o.w = T[mm+3][kk];
        *reinterpret_cast<float4*>(&XT[(size_t)(k0+kk)*MTOT + m0 + mm]) = o;
    }
}

// ========== GEMM1: CUR = X @ Win + bin, strict f32 (bitwise-np) =============
// Structure plateau (R3/R9/R10 all ~210us): keep R10's 3-stage gld_lds
// pipeline unchanged. Numerics: single accumulator per output, fmaf over k
// ASCENDING — bitwise vs numpy reference; spikes feed back. DO NOT ALTER.
__global__ __launch_bounds__(256) void gemm1_f32(
    const float* __restrict__ XT, const float* __restrict__ Win,
    const float* __restrict__ bin, float* __restrict__ CUR)
{
    __shared__ __align__(16) float As[3][16][128];   // [stage][k][m]
    __shared__ __align__(16) float Bs[3][16][256];   // [stage][k][n]
    const int bm = blockIdx.x * 128;
    const int bn = blockIdx.y * 256;
    const int t  = threadIdx.x;
    const int lane = t & 63, w = t >> 6;  // 4 waves
    const int tx = t & 15, ty = t >> 4;
    float acc[8][16] = {};

    #define G1_STAGE_A(sb_, k0_) do { \
        _Pragma("unroll") \
        for (int q = 0; q < 2; ++q) { \
            const int rbase = w*4 + q*2; \
            gld_lds16(&XT[(size_t)((k0_)+rbase+(lane>>5))*MTOT + bm + (lane&31)*4], \
                      &As[sb_][rbase][0]); \
        } \
    } while (0)
    #define G1_STAGE_B(sb_, k0_) do { \
        _Pragma("unroll") \
        for (int q = 0; q < 4; ++q) { \
            const int r = q*4 + w; \
            gld_lds16(&Win[(size_t)((k0_)+r)*DH + bn + lane*4], &Bs[sb_][r][0]); \
        } \
    } while (0)
    #define G1_COMPUTE(sb_) do { \
        _Pragma("unroll 4") \
        for (int kk = 0; kk < 16; ++kk) { \
            float a[8], b[16]; \
            float4 a0 = *reinterpret_cast<const float4*>(&As[sb_][kk][ty*8]); \
            float4 a1 = *reinterpret_cast<const float4*>(&As[sb_][kk][ty*8+4]); \
            a[0]=a0.x; a[1]=a0.y; a[2]=a0.z; a[3]=a0.w; \
            a[4]=a1.x; a[5]=a1.y; a[6]=a1.z; a[7]=a1.w; \
            _Pragma("unroll") \
            for (int g = 0; g < 4; ++g) { \
                float4 bq = *reinterpret_cast<const float4*>(&Bs[sb_][kk][g*64 + tx*4]); \
                b[g*4+0]=bq.x; b[g*4+1]=bq.y; b[g*4+2]=bq.z; b[g*4+3]=bq.w; \
            } \
            _Pragma("unroll") \
            for (int i = 0; i < 8; ++i) \
                _Pragma("unroll") \
                for (int j = 0; j < 16; ++j) \
                    acc[i][j] = fmaf(a[i], b[j], acc[i][j]); \
        } \
    } while (0)

    G1_STAGE_A(0, 0);  G1_STAGE_B(0, 0);
    G1_STAGE_A(1, 16); G1_STAGE_B(1, 16);

    #pragma unroll 1
    for (int tI = 0; tI < 15; ++tI) {
        const int sb = tI % 3;
        asm volatile("s_waitcnt vmcnt(6)" ::: "memory");
        __builtin_amdgcn_sched_barrier(0);
        __builtin_amdgcn_s_barrier();
        __builtin_amdgcn_sched_barrier(0);
        G1_COMPUTE(sb);
        __builtin_amdgcn_sched_barrier(0);
        __builtin_amdgcn_s_barrier();
        __builtin_amdgcn_sched_barrier(0);
        if (tI + 2 < 16) {
            const int k2 = (tI + 2) * 16;
            const int s2 = (tI + 2) % 3;
            G1_STAGE_A(s2, k2);
            G1_STAGE_B(s2, k2);
        }
    }
    asm volatile("s_waitcnt vmcnt(0)" ::: "memory");
    __builtin_amdgcn_sched_barrier(0);
    __builtin_amdgcn_s_barrier();
    __builtin_amdgcn_sched_barrier(0);
    G1_COMPUTE(0);

    #pragma unroll
    for (int i = 0; i < 8; ++i) {
        const int row = bm + ty*8 + i;
        #pragma unroll
        for (int g = 0; g < 4; ++g) {
            const int col = bn + g*64 + tx*4;
            float4 o;
            o.x = __fadd_rn(acc[i][g*4+0], bin[col+0]);
            o.y = __fadd_rn(acc[i][g*4+1], bin[col+1]);
            o.z = __fadd_rn(acc[i][g*4+2], bin[col+2]);
            o.w = __fadd_rn(acc[i][g*4+3], bin[col+3]);
            *reinterpret_cast<float4*>(&CUR[(size_t)row*DH + col]) = o;
        }
    }
}

// ========== scan: strict-f32 recurrence, 32-deep pipeline, u8 spikes ========
__global__ __launch_bounds__(256) void scan_k(
    const float* __restrict__ CUR, const float* __restrict__ wrec,
    u8* __restrict__ SPK, unsigned int* __restrict__ cnt)
{
    const int i = blockIdx.x*256 + threadIdx.x;
    float v = 0.0f;                       // V0 = 0
    const float w = wrec[i & (DH-1)];
    int c = 0;
    float cur[32], nxt[32];
    #pragma unroll
    for (int u = 0; u < 32; ++u) cur[u] = CUR[(size_t)u*NV + i];
    for (int t0 = 0; t0 < TT; t0 += 32) {
        if (t0 + 32 < TT) {
            #pragma unroll
            for (int u = 0; u < 32; ++u) nxt[u] = CUR[(size_t)(t0+32+u)*NV + i];
        }
        u8 sp[32];
        #pragma unroll
        for (int u = 0; u < 32; ++u) {
            const bool s = v > 1.0f;      // (V-1>0) <=> V>1 exactly in f32
            sp[u] = s ? (u8)1 : (u8)0;
            c += (int)s;
            float t1 = __fmul_rn(0.9f, v);
            float t2 = __fadd_rn(t1, cur[u]);
            float t3 = __fadd_rn(t2, s ? w : 0.0f);
            v = __fsub_rn(t3, s ? 1.0f : 0.0f);
        }
        #pragma unroll
        for (int u = 0; u < 32; ++u) SPK[(size_t)(t0+u)*NV + i] = sp[u];
        #pragma unroll
        for (int u = 0; u < 32; ++u) cur[u] = nxt[u];
    }
    #pragma unroll
    for (int o = 32; o > 0; o >>= 1) c += __shfl_down(c, o, 64);
    if ((threadIdx.x & 63) == 0) atomicAdd(cnt, (unsigned int)c);
}

// ========== W_head -> bf16 transposed [DOUT][DH] ============================
__global__ __launch_bounds__(256) void trsp_k(
    const float* __restrict__ Wh, u16* __restrict__ WhT)
{
    const int id = blockIdx.x*256 + threadIdx.x;   // DOUT*DH
    const int n = id >> 9, k = id & (DH-1);
    __hip_bfloat16 h = __float2bfloat16(Wh[(size_t)k*DOUT + n]);
    WhT[id] = *reinterpret_cast<u16*>(&h);
}

// ========== GEMM2: logits = SPK(u8) @ Whead + bhead, bf16 MFMA ==============
// 128x128 tile, 4 waves (2x2), BK=32, 16x16x32 MFMA, double-buffered LDS,
// one barrier per k-step. A loaded as u8 (halves SPK read traffic), expanded
// to bf16 in regs during staging -> LDS layout & swizzle identical to R10.
__global__ __launch_bounds__(256) void gemm2_mfma(
    const u8* __restrict__ SPK, const u16* __restrict__ WhT,
    const float* __restrict__ bh, float* __restrict__ Y)
{
    __shared__ __align__(16) u16 Ab[2][128*32];
    __shared__ __align__(16) u16 Bb[2][128*32];
    const int bm = blockIdx.x * 128;
    const int bn = blockIdx.y * 128;
    const int t = threadIdx.x;
    const int lane = t & 63, wid = t >> 6;
    const int wr = wid >> 1, wc = wid & 1;
    const int srow = t >> 1, shf = t & 1;
    uint64_t va8[2];
    uint4 vb[2];
    f32x4 acc[4][4];
    #pragma unroll
    for (int m = 0; m < 4; ++m)
        #pragma unroll
        for (int n = 0; n < 4; ++n) acc[m][n] = (f32x4){0.f,0.f,0.f,0.f};

    #define G2_LOAD(k0) do { \
        _Pragma("unroll") \
        for (int q = 0; q < 2; ++q) { \
            const int c = shf*2 + q; \
            va8[q] = *reinterpret_cast<const uint64_t*>(&SPK[(size_t)(bm+srow)*DH + (k0) + c*8]); \
            vb[q] = *reinterpret_cast<const uint4*>(&WhT[(size_t)(bn+srow)*DH + (k0) + c*8]); \
        } \
    } while (0)
    #define G2_WRITE(nb) do { \
        _Pragma("unroll") \
        for (int q = 0; q < 2; ++q) { \
            const int c = shf*2 + q; \
            *reinterpret_cast<uint4*>(&Ab[nb][srow*32 + ((c ^ (srow&3))*8)]) = expand8(va8[q]); \
            *reinterpret_cast<uint4*>(&Bb[nb][srow*32 + ((c ^ (srow&3))*8)]) = vb[q]; \
        } \
    } while (0)

    G2_LOAD(0);
    G2_WRITE(0);
    __syncthreads();

    int nb = 0;
    for (int k0 = 0; k0 < DH; k0 += 32) {
        const int nxt = k0 + 32;
        if (nxt < DH) G2_LOAD(nxt);
        const int l15 = lane & 15, lc = lane >> 4;
        bf16x8 af[4], bfr[4];
        #pragma unroll
        for (int m = 0; m < 4; ++m) {
            const int r = wr*64 + m*16 + l15;
            af[m] = *reinterpret_cast<const bf16x8*>(&Ab[nb][r*32 + ((lc ^ (r&3))*8)]);
        }
        #pragma unroll
        for (int n = 0; n < 4; ++n) {
            const int r = wc*64 + n*16 + l15;
            bfr[n] = *reinterpret_cast<const bf16x8*>(&Bb[nb][r*32 + ((lc ^ (r&3))*8)]);
        }
        #pragma unroll
        for (int m = 0; m < 4; ++m)
            #pragma unroll
            for (int n = 0; n < 4; ++n)
                acc[m][n] = __builtin_amdgcn_mfma_f32_16x16x32_bf16(
                    af[m], bfr[n], acc[m][n], 0, 0, 0);
        if (nxt < DH) G2_WRITE(nb^1);
        __syncthreads();
        nb ^= 1;
    }
    // epilogue: D col = lane&15, row = (lane>>4)*4 + r
    #pragma unroll
    for (int m = 0; m < 4; ++m)
        #pragma unroll
        for (int n = 0; n < 4; ++n) {
            const int row0 = bm + wr*64 + m*16 + (lane >> 4)*4;
            const int col  = bn + wc*64 + n*16 + (lane & 15);
            const float bv = bh[col];
            #pragma unroll
            for (int r = 0; r < 4; ++r)
                Y[(size_t)(row0 + r)*DOUT + col] = acc[m][n][r] + bv;
        }
}

// ========== readout: mean over T (two-stage, deterministic) =================
__global__ __launch_bounds__(256) void readout1(
    const float* __restrict__ L, double* __restrict__ P)
{
    const int j = blockIdx.x*256 + threadIdx.x;
    const int p = blockIdx.y;
    double s = 0.0;
    for (int u = 0; u < 64; ++u)
        s += (double)L[(size_t)(p*64 + u)*NLOG + j];
    P[(size_t)p*NLOG + j] = s;
}
__global__ __launch_bounds__(256) void readout2(
    const double* __restrict__ P, float* __restrict__ R,
    const unsigned int* __restrict__ cnt, float* __restrict__ srate)
{
    const int j = blockIdx.x*256 + threadIdx.x;
    double s = 0.0;
    #pragma unroll
    for (int p = 0; p < 8; ++p) s += P[(size_t)p*NLOG + j];
    R[j] = (float)(s / (double)TT);
    if (j == 0)
        srate[0] = (float)((double)cnt[0] / ((double)TT * (double)NV));
}

// ============================================================================
extern "C" void kernel_launch(void* const* d_in, const int* in_sizes, int n_in,
                              void* d_out, int out_size, void* d_ws, size_t ws_size,
                              hipStream_t stream)
{
    const float* x     = (const float*)d_in[0];   // [512][128][256]
    const float* Win   = (const float*)d_in[1];   // [256][512]
    const float* bin   = (const float*)d_in[2];   // [512]
    const float* wrec  = (const float*)d_in[3];   // [512]
    const float* Whead = (const float*)d_in[4];   // [512][256]
    const float* bhead = (const float*)d_in[5];   // [256]

    float* out     = (float*)d_out;
    float* readout = out;                           // 32768
    float* logits  = out + NLOG;                    // 512*32768
    float* srate   = out + NLOG + (size_t)TT*NLOG;  // 1

    char* w = (char*)d_ws;
    size_t off = 0;
    float* CUR = (float*)(w + off);  off += (size_t)TT*NV*4;      // 128 MB
    // 64 MB region: first 32 MB = SPK (u8), full 64 MB doubles as XT overlay
    u8*    SPK = (u8*)   (w + off);
    float* XT  = (float*)(w + off);  off += (size_t)TT*NV*2;      //  64 MB
    u16*   WhT = (u16*)  (w + off);  off += (size_t)DOUT*DH*2;    // 256 KB
    double* P  = (double*)(w + off); off += (size_t)8*NLOG*8;     //   2 MB
    unsigned int* cnt = (unsigned int*)(w + off);

    hipMemsetAsync(cnt, 0, 256, stream);
    trspX_k<<<dim3(MTOT/64, DIN/64), 256, 0, stream>>>(x, XT);
    trsp_k<<<DOUT*DH/256, 256, 0, stream>>>(Whead, WhT);
    gemm1_f32<<<dim3(MTOT/128, DH/256), 256, 0, stream>>>(XT, Win, bin, CUR);
    scan_k<<<NV/256, 256, 0, stream>>>(CUR, wrec, SPK, cnt);
    gemm2_mfma<<<dim3(MTOT/128, DOUT/128), 256, 0, stream>>>(SPK, WhT, bhead, logits);
    readout1<<<dim3(NLOG/256, 8), 256, 0, stream>>>(logits, P);
    readout2<<<NLOG/256, 256, 0, stream>>>(P, readout, cnt, srate);
}